// Round 14
// baseline (570.749 us; speedup 1.0000x reference)
//
#include <hip/hip_runtime.h>
#include <stdint.h>

// Sizes: x [16,1,512,512] f32 binary; weight [1024,512] f32; out [16,1,1024,529] f32.
// pot[b,o,t'] = sum_tau K(w[o,i],tau) * x[b,i,t'+15-tau] + 12.8
// K via cumsum^2 of its Delta^2; tap pairs scattered at spike positions into per-(wave,ramp)
// float2 LDS planes; WTA depression uniform -> per-batch serial scan.
// Ledger: R14/R21 scatter (dustbin-min, 4 blk/CU, pot write) = 362us best; ~73% LDS-pipe
// util vs ~637K cyc/CU irreducible DS demand.
//   R12/R21: bank conflicts = random-collision floor (per-instruction bank multiset is
//     reorder/layout/hash-invariant; all <=32 spikes of a row share one instruction).
//   R10/R16: LDS atomics serialize per lane (~78 cyc) -> dead.
//   R19: 90% occupancy regressed (DS instruction density dominates).
//   R20: exec-mask guard per RMW costs more than dustbin bank cycles.
//   R22: fused-argmax u64 atomicMax cost +22us in scatter (68MB L2 write-through +
//     drain) vs 14us saved -> reverted. 2e6 device atomics > 34MB stream write + read.
// R23: best structure (R21) + dispatch-count 8->6: k_spikes+k_taps merged into k_prep
// (blockIdx branch); k_argmax2 combine merged into k_wta phase 1. Scatter byte-identical.

#define NB 16
#define NI 512
#define NT 512
#define NO 1024
#define TOUT 529
#define SCAP 96           // spike capacity per (b,i); max observed ~48
#define OTILE 4
#define PLANE 570         // cells 0..560 live, 561..568 spread dustbin, pad->570
#define THETA_F 25.6f
#define BIAS_T 12.8f

// ---------- P2 helper: kernel value (exact same expression as reference) ----------
__device__ __forceinline__ float kval(float b15, int tau) {
    if (tau > 47) return 0.f;
    float f = (float)tau * 0.0625f;
    float g = b15 - (float)tau * 0.03125f;
    return fmaxf(0.f, fminf(f, g));
}

// ---------- P1+P2 merged: blocks [0,2048) = spike lists; [2048,4096) = taps ----------
__global__ __launch_bounds__(256) void k_prep(const float* __restrict__ x,
                                              const float* __restrict__ weight,
                                              unsigned short* __restrict__ slist,
                                              unsigned int* __restrict__ spkw,
                                              unsigned int* __restrict__ counts,
                                              float* __restrict__ hg,
                                              float4* __restrict__ tap) {
    __shared__ unsigned short sls[4][SCAP];
    if (blockIdx.x < 2048) {
        // ---- spike list (LDS-staged) + packed byte-scaled words + counts + hist ----
        int wq = threadIdx.x >> 6, lane = threadIdx.x & 63;
        int row = blockIdx.x * 4 + wq;             // row = b*512 + i
        int b = row >> 9;
        const float* xr = x + (size_t)row * NT;
        for (int j = lane; j < SCAP; j += 64) sls[wq][j] = 0x1FFF;  // <<3 = 0xFFF8 sentinel
        int base = 0;
        for (int kk = 0; kk < 8; ++kk) {
            int t = kk * 64 + lane;
            bool pred = xr[t] > 0.5f;
            unsigned long long mask = __ballot(pred);
            int pre = __popcll(mask & ((1ull << lane) - 1ull));
            int pos = base + pre;
            if (pred) {
                if (pos < SCAP) sls[wq][pos] = (unsigned short)t;
                unsafeAtomicAdd(&hg[b * NT + t], 1.0f);   // integer counts: exact any order
            }
            base += __popcll(mask);
        }
        __syncthreads();
        if (lane < SCAP / 2) {                     // full raw list for cold path
            unsigned v = (unsigned)sls[wq][2 * lane] | ((unsigned)sls[wq][2 * lane + 1] << 16);
            ((unsigned int*)(slist + (size_t)row * SCAP))[lane] = v;
        }
        if (lane < 32)                             // packed (k, k+32) pair words, BYTE-scaled
            spkw[(size_t)row * 32 + lane] =
                ((unsigned)sls[wq][lane] << 3) | ((unsigned)sls[wq][lane + 32] << 19);
        if (lane == 0) counts[row] = (unsigned)min(base, SCAP);
    } else {
        // ---- per-(o,i) taps via candidate ranges (bit-identical to 50-iter loop) ----
        // tap[((o*512+i)*2 + ramp)] = float4(v1, v2, pos8_bits, 0). Missing: pos8=16384.
        int p = (blockIdx.x - 2048) * 256 + threadIdx.x;   // i fast -> coalesced
        int o = p >> 9, i = p & 511;
        float w = weight[o * NI + i];
        float b15 = 1.5f * w;
        float vA1 = 0.f, vA2 = 0.f, vB1 = 0.f, vB2 = 0.f;
        int posA = 2048, posB = 2048, state = 0;
        // d(tau) nonzero only near kinks s1=16w, s2=48w (+-1 widened) and onset.
        int n1 = (int)floorf(16.0f * w);
        int n2 = (int)floorf(48.0f * w);
        int lo1 = max(n1, 1);
        int hi1, lo2, hi2;
        if (n2 <= n1 + 4) { hi1 = min(n2 + 3, 49); lo2 = 1; hi2 = 0; }   // merged
        else             { hi1 = min(n1 + 3, 49); lo2 = n2; hi2 = min(n2 + 3, 49); }

#define TAPRUN(LO, HI)                                                                \
        {                                                                             \
            float Km1 = kval(b15, (LO) - 1), Km2 = kval(b15, (LO) - 2);               \
            for (int tau = (LO); tau <= (HI); ++tau) {                                \
                float K = kval(b15, tau);                                             \
                float d = (K - Km1) - (Km1 - Km2);                                    \
                if (tau == 1) d -= 0.0625f;        /* onset -> histogram */           \
                if (d != 0.f) {                                                       \
                    if (state == 0)      { posA = tau; vA1 = d; state = 1; }          \
                    else if (state == 1) { if (tau == posA + 1) { vA2 = d; state = 2; }\
                                           else { posB = tau; vB1 = d; state = 3; } } \
                    else if (state == 2) { posB = tau; vB1 = d; state = 3; }          \
                    else if (state == 3) { if (tau == posB + 1) { vB2 = d; state = 4; } }\
                }                                                                     \
                Km2 = Km1; Km1 = K;                                                   \
            }                                                                         \
        }
        TAPRUN(lo1, hi1)
        if (lo2 <= hi2) TAPRUN(lo2, hi2)

        size_t base2 = 2 * ((size_t)o * NI + i);
        tap[base2]     = make_float4(vA1, vA2, __int_as_float(posA >= 2048 ? 16384 : posA * 8), 0.f);
        tap[base2 + 1] = make_float4(vB1, vB2, __int_as_float(posB >= 2048 ? 16384 : posB * 8), 0.f);
    }
}

// ---------- P3: wave-exclusive-plane float2 RMW scatter (BYTE-IDENTICAL R14 core) ----------
// Wave w owns float2 planes (w,ramp0),(w,ramp1). Lane: k=lane>>1 spike slot, ramp=lane&1.
// Byte addressing: e8 = min(t8 + p8, dcap8); dcap8 = (561+(k&7))*8 spread dustbin.
// Non-atomic RMW race-free: distinct spike times per lane within a plane.
#define PROC(TP, WV, CNT, IDX)                                                        \
    {                                                                                 \
        const int p8 = __float_as_int((TP).z);                                        \
        {                                                                             \
            int e8 = min((int)((WV) & 0xFFFFu) + p8, dcap8);                          \
            float2* cell = (float2*)((char*)accw + e8);                               \
            float2 v = *cell; v.x += (TP).x; v.y += (TP).y; *cell = v;                \
        }                                                                             \
        if ((CNT) > 32u) {                                                            \
            int e8 = min((int)((WV) >> 16) + p8, dcap8);                              \
            float2* cell = (float2*)((char*)accw + e8);                               \
            float2 v = *cell; v.x += (TP).x; v.y += (TP).y; *cell = v;                \
        }                                                                             \
        if ((CNT) > 64u) {                                                            \
            const unsigned short* sr = slist + (size_t)(b * NI + (IDX)) * SCAP;       \
            for (int kk = 64 + k; kk < (int)(CNT); kk += 32) {                        \
                int e8 = min(((int)sr[kk] << 3) + p8, dcap8);                         \
                float2* cell = (float2*)((char*)accw + e8);                           \
                float2 v = *cell; v.x += (TP).x; v.y += (TP).y; *cell = v;            \
            }                                                                         \
        }                                                                             \
    }

__global__ __launch_bounds__(256, 4) void k_scatter(const unsigned short* __restrict__ slist,
                                                    const unsigned int* __restrict__ spkw,
                                                    const unsigned int* __restrict__ counts,
                                                    const float4* __restrict__ tap,
                                                    const float* __restrict__ hg,
                                                    float* __restrict__ pot) {
    __shared__ __align__(16) float2 acc[OTILE * 2 * PLANE];  // 36,480 B
    __shared__ double pub[512];                              // 4,096 B -> 40,832: 4 blk/CU
    const int o0 = blockIdx.x * OTILE;
    const int b  = blockIdx.y;
    const int tid = threadIdx.x;
    const int w = tid >> 6, lane = tid & 63;
    const int k = lane >> 1, ramp = lane & 1;
    const int dcap8 = (561 + (k & 7)) * 8;         // spread dustbin, loop-invariant

    for (int idx = tid; idx < OTILE * PLANE; idx += 256)     // 2280 float4s = whole acc
        ((float4*)acc)[idx] = make_float4(0.f, 0.f, 0.f, 0.f);
    __syncthreads();

    float2* accw = acc + (w * 2 + ramp) * PLANE;   // my (wave, ramp) plane
    const unsigned int* wrow = spkw + (size_t)(b * NI) * 32 + k;
    const float4* trow = tap + 2 * (size_t)(o0 + w) * NI + ramp;
    const uint4* crow = (const uint4*)(counts + b * NI);

    // prefetch quad 0 (statically-named scalars -> registers; R9 lesson)
    float4 ntA = trow[0], ntB = trow[2], ntC = trow[4], ntD = trow[6];
    unsigned nwA = wrow[0], nwB = wrow[32], nwC = wrow[64], nwD = wrow[96];
    uint4 ncc = crow[0];

    const int NIQ = NI / 4;
    for (int iq = 0; iq < NIQ; ++iq) {
        const float4 tA = ntA, tB = ntB, tC = ntC, tD = ntD;
        const unsigned wA = nwA, wB = nwB, wC = nwC, wD = nwD;
        const uint4 cc = ncc;
        if (iq + 1 < NIQ) {                        // prefetch next quad
            const float4* tb = trow + (size_t)(iq + 1) * 8;
            ntA = tb[0]; ntB = tb[2]; ntC = tb[4]; ntD = tb[6];
            const unsigned int* wb = wrow + (size_t)(iq + 1) * 128;
            nwA = wb[0]; nwB = wb[32]; nwC = wb[64]; nwD = wb[96];
            ncc = crow[iq + 1];
        }
        const int i0 = iq * 4;
        PROC(tA, wA, cc.x, i0)
        PROC(tB, wB, cc.y, i0 + 1)
        PROC(tC, wC, cc.z, i0 + 2)
        PROC(tD, wD, cc.w, i0 + 3)
    }
    __syncthreads();

    // ---- cumsum^2 (double): thread (oo=w, q=lane) owns cells [9q, 9q+9) ----
    const int q = lane;
    const float2* pr0 = acc + (w * 2) * PLANE;
    const float2* pr1 = pr0 + PLANE;
    const float* hb = hg + b * NT;
    double dsv[9];
    double s1d = 0.0, s2d = 0.0;
#pragma unroll
    for (int r = 0; r < 9; ++r) {
        int e = q * 9 + r;
        double d = 0.0;
        if (e < 561) {
            float2 c0 = pr0[e], c1 = pr1[e];
            d = (double)c0.x + (double)c1.x;
            if (e >= 1) {
                float2 m0 = pr0[e - 1], m1 = pr1[e - 1];
                d += (double)m0.y + (double)m1.y;           // v2 planes: shifted +1
                if (e <= 512) d += 0.0625 * (double)hb[e - 1];   // onset histogram
            }
        }
        dsv[r] = d; s1d += d; s2d += s1d;
    }
    pub[2 * tid] = s1d; pub[2 * tid + 1] = s2d;
    __syncthreads();
    if (tid < 4) {                                 // serial carry scan per o-row
        double c1 = 0.0, c2 = 0.0;
        for (int qq = 0; qq < 64; ++qq) {
            int j = (tid << 6) + qq;
            double S1 = pub[2 * j], S2 = pub[2 * j + 1];
            pub[2 * j] = c1; pub[2 * j + 1] = c2;
            c2 += 9.0 * c1 + S2;
            c1 += S1;
        }
    }
    __syncthreads();
    {
        const double C1 = pub[2 * tid], C2 = pub[2 * tid + 1];
        double a1 = 0.0, a2 = 0.0;
        float2* rowW = acc + (w * 2) * PLANE;
#pragma unroll
        for (int r = 0; r < 9; ++r) {
            a1 += dsv[r]; a2 += a1;
            int e = q * 9 + r;
            if (e < 561) rowW[e].x = (float)(C2 + C1 * (double)(r + 1) + a2);
        }
    }
    __syncthreads();
    for (int oo = 0; oo < OTILE; ++oo)             // coalesced pot write (t fastest)
        for (int t = tid; t < TOUT; t += 256)
            pot[((size_t)(b * NO + o0 + oo)) * TOUT + t] = acc[(oo * 2) * PLANE + t + 15].x + BIAS_T;
}

// ---------- P4a: partial argmax over 128-o chunks (1152 blocks) ----------
__global__ __launch_bounds__(256) void k_argmax1(const float* __restrict__ pot,
                                                 float* __restrict__ pval,
                                                 unsigned short* __restrict__ pidx) {
    __shared__ float sv[4][64];
    __shared__ int   si[4][64];
    int b = blockIdx.y, c = blockIdx.z;
    int lane = threadIdx.x & 63, grp = threadIdx.x >> 6;
    int t = blockIdx.x * 64 + lane;
    bool valid = t < TOUT;
    float best = -1.f; int bidx = 0;
    if (valid) {
        int ob = c * 128 + grp * 32;
        for (int od = 0; od < 32; ++od) {          // ascending o + strict '>' => first max wins
            int o = ob + od;
            float v = pot[((size_t)(b * NO + o)) * TOUT + t];
            if (v > best) { best = v; bidx = o; }
        }
    }
    sv[grp][lane] = best; si[grp][lane] = bidx;
    __syncthreads();
    if (grp == 0 && valid) {
#pragma unroll
        for (int g = 1; g < 4; ++g) {              // ascending grp = ascending o
            float v = sv[g][lane];
            if (v > best) { best = v; bidx = si[g][lane]; }
        }
        pval[((size_t)(c * NB + b)) * TOUT + t] = best;
        pidx[((size_t)(c * NB + b)) * TOUT + t] = (unsigned short)bidx;
    }
}

// ---------- P4b+P5 merged: 8-chunk combine + serial refractory scan ----------
__global__ __launch_bounds__(256) void k_wta(const float* __restrict__ pval,
                                             const unsigned short* __restrict__ pidx,
                                             float* __restrict__ out) {
    __shared__ float lv[TOUT * NB];
    __shared__ unsigned short li[TOUT * NB];
    for (int idx = threadIdx.x; idx < TOUT * NB; idx += 256) {
        int t = idx >> 4, b = idx & 15;            // lv layout: [t][b]
        float best = -1.f; int bidx = 0;
#pragma unroll
        for (int c = 0; c < 8; ++c) {              // ascending chunk = ascending o
            size_t pidx_ = ((size_t)(c * NB + b)) * TOUT + t;
            float v = pval[pidx_];
            if (v > best) { best = v; bidx = pidx[pidx_]; }
        }
        lv[idx] = best; li[idx] = (unsigned short)bidx;
    }
    __syncthreads();
    int b = threadIdx.x;
    if (b < NB) {
        int r = 0;
        for (int t = 0; t < TOUT; ++t) {
            float v = lv[t * NB + b];
            if (r == 0 && v > THETA_F) {
                int n = (int)li[t * NB + b];
                out[((size_t)(b * NO + n)) * TOUT + t] = 1.0f;
                r = 48;
            }
            r = max(r - 1, 0);
        }
    }
}

extern "C" void kernel_launch(void* const* d_in, const int* in_sizes, int n_in,
                              void* d_out, int out_size, void* d_ws, size_t ws_size,
                              hipStream_t stream) {
    const float* x      = (const float*)d_in[0];   // [16,1,512,512]
    const float* weight = (const float*)d_in[1];   // [1024,512]
    float* out = (float*)d_out;                    // [16,1,1024,529]
    char* ws = (char*)d_ws;
    // ws layout (~19.9 MB)
    unsigned short* slist  = (unsigned short*)(ws);            // 8192*96*2     = 1,572,864
    unsigned int*   spkw   = (unsigned int*)(ws + 1572864);    // 8192*32*4     = 1,048,576
    unsigned int*   counts = (unsigned int*)(ws + 2621440);    // 8192*4        = 32,768
    float4*         tap    = (float4*)(ws + 2654208);          // 1024*512*2*16 = 16,777,216
    float*          hg     = (float*)(ws + 19431424);          // 16*512*4      = 32,768
    float*          pval   = (float*)(ws + 19464192);          // 8*16*529*4    = 270,848
    unsigned short* pidx   = (unsigned short*)(ws + 19735040); // 8*16*529*2    = 135,424

    hipMemsetAsync(hg, 0, NB * NT * sizeof(float), stream);    // before k_prep (hist fused)
    k_prep<<<4096, 256, 0, stream>>>(x, weight, slist, spkw, counts, hg, tap);
    k_scatter<<<dim3(NO / OTILE, NB), 256, 0, stream>>>(slist, spkw, counts, tap, hg, out);
    k_argmax1<<<dim3(9, NB, 8), 256, 0, stream>>>(out, pval, pidx);
    hipMemsetAsync(d_out, 0, (size_t)out_size * sizeof(float), stream);   // clear pot scratch
    k_wta<<<1, 256, 0, stream>>>(pval, pidx, out);                        // combine + spikes
}

// Round 15
// 490.022 us; speedup vs baseline: 1.1647x; 1.1647x over previous
//
#include <hip/hip_runtime.h>
#include <stdint.h>

// Sizes: x [16,1,512,512] f32 binary; weight [1024,512] f32; out [16,1,1024,529] f32.
// pot[b,o,t'] = sum_tau K(w[o,i],tau) * x[b,i,t'+15-tau] + 12.8
// K via cumsum^2 of its Delta^2; tap pairs scattered at spike positions into
// per-(wave,ramp) float2 LDS planes; WTA depression uniform -> per-batch serial scan.
// FINAL (R24 = byte-identical resubmit of R14, the measured best: 490.3us total,
// scatter 362-366us). Complete lever ledger:
//   R12/R21: bank conflicts = random-collision floor; per-instruction bank multiset
//     is invariant under reorder/layout/hash (all <=32 spikes of a row share one
//     wave instruction). ~5 extra cyc/instr irreducible.
//   R10/R16: LDS float atomics serialize PER LANE (~78 cyc/op, 10x+ worse). Dead.
//   R19: 90% occupancy via 1-o-blocks regressed 1.5x (DS instruction density
//     dominates; (k,ramp) 64-lane packing + cnt-gating is the dense form).
//   R20: per-RMW exec-mask guards cost more than dustbin bank cycles (+11%).
//   R22: fused-argmax u64 atomicMax: 2e6 device atomics > 34MB scratch write+read.
//   R23: dispatch merging: single-block combine serialization (+40us) > launch gaps.
// Scatter sits at ~73% util of irreducible ~637K cyc/CU DS demand; RMW chain-breaking
// is unsafe (cross-lane aliasing). Non-scatter stages (~128us) individually at their
// memory/latency floors. This is the structural floor of this algorithm on MI355X.

#define NB 16
#define NI 512
#define NT 512
#define NO 1024
#define TOUT 529
#define SCAP 96           // spike capacity per (b,i); max observed ~48
#define OTILE 4
#define PLANE 570         // cells 0..560 live, 561..568 spread dustbin, pad->570
#define THETA_F 25.6f
#define BIAS_T 12.8f

// ---------- P1: spike list (LDS-staged) + packed byte-scaled words + counts + hist ----------
__global__ __launch_bounds__(256) void k_spikes(const float* __restrict__ x,
                                                unsigned short* __restrict__ slist,
                                                unsigned int* __restrict__ spkw,
                                                unsigned int* __restrict__ counts,
                                                float* __restrict__ hg) {
    __shared__ unsigned short sls[4][SCAP];
    int wq = threadIdx.x >> 6, lane = threadIdx.x & 63;
    int row = blockIdx.x * 4 + wq;                 // row = b*512 + i
    int b = row >> 9;
    const float* xr = x + (size_t)row * NT;
    for (int j = lane; j < SCAP; j += 64) sls[wq][j] = 0x1FFF;   // 0x1FFF<<3 = 0xFFF8 sentinel
    int base = 0;
    for (int kk = 0; kk < 8; ++kk) {
        int t = kk * 64 + lane;
        bool pred = xr[t] > 0.5f;
        unsigned long long mask = __ballot(pred);
        int pre = __popcll(mask & ((1ull << lane) - 1ull));
        int pos = base + pre;
        if (pred) {
            if (pos < SCAP) sls[wq][pos] = (unsigned short)t;
            unsafeAtomicAdd(&hg[b * NT + t], 1.0f);   // integer counts: exact any order
        }
        base += __popcll(mask);
    }
    __syncthreads();
    if (lane < SCAP / 2) {                         // full raw list for cold path
        unsigned v = (unsigned)sls[wq][2 * lane] | ((unsigned)sls[wq][2 * lane + 1] << 16);
        ((unsigned int*)(slist + (size_t)row * SCAP))[lane] = v;
    }
    if (lane < 32)                                 // packed (k, k+32) pair words, BYTE-scaled
        spkw[(size_t)row * 32 + lane] =
            ((unsigned)sls[wq][lane] << 3) | ((unsigned)sls[wq][lane + 32] << 19);
    if (lane == 0) counts[row] = (unsigned)min(base, SCAP);
}

// ---------- P2: per-(o,i) taps via candidate ranges (bit-identical to 50-iter loop) ----------
// tap[((o*512+i)*2 + ramp)] = float4(v1, v2, pos8_as_int_bits, 0). Missing pair: pos8=16384.
__device__ __forceinline__ float kval(float b15, int tau) {
    if (tau > 47) return 0.f;
    float f = (float)tau * 0.0625f;
    float g = b15 - (float)tau * 0.03125f;
    return fmaxf(0.f, fminf(f, g));
}

__global__ __launch_bounds__(256) void k_taps(const float* __restrict__ weight,
                                              float4* __restrict__ tap) {
    int p = blockIdx.x * 256 + threadIdx.x;        // 512*1024; i fast -> coalesced
    int o = p >> 9, i = p & 511;
    float w = weight[o * NI + i];
    float b15 = 1.5f * w;
    float vA1 = 0.f, vA2 = 0.f, vB1 = 0.f, vB2 = 0.f;
    int posA = 2048, posB = 2048, state = 0;
    // d(tau) nonzero only near the two kinks s1=16w, s2=48w (+-1 widened) and onset.
    int n1 = (int)floorf(16.0f * w);
    int n2 = (int)floorf(48.0f * w);
    int lo1 = max(n1, 1);
    int hi1, lo2, hi2;
    if (n2 <= n1 + 4) { hi1 = min(n2 + 3, 49); lo2 = 1; hi2 = 0; }   // merged, range2 empty
    else             { hi1 = min(n1 + 3, 49); lo2 = n2; hi2 = min(n2 + 3, 49); }

#define TAPRUN(LO, HI)                                                                \
    {                                                                                 \
        float Km1 = kval(b15, (LO) - 1), Km2 = kval(b15, (LO) - 2);                   \
        for (int tau = (LO); tau <= (HI); ++tau) {                                    \
            float K = kval(b15, tau);                                                 \
            float d = (K - Km1) - (Km1 - Km2);                                        \
            if (tau == 1) d -= 0.0625f;            /* onset -> histogram */           \
            if (d != 0.f) {                                                           \
                if (state == 0)      { posA = tau; vA1 = d; state = 1; }              \
                else if (state == 1) { if (tau == posA + 1) { vA2 = d; state = 2; }   \
                                       else { posB = tau; vB1 = d; state = 3; } }     \
                else if (state == 2) { posB = tau; vB1 = d; state = 3; }              \
                else if (state == 3) { if (tau == posB + 1) { vB2 = d; state = 4; } } \
            }                                                                         \
            Km2 = Km1; Km1 = K;                                                       \
        }                                                                             \
    }
    TAPRUN(lo1, hi1)
    if (lo2 <= hi2) TAPRUN(lo2, hi2)

    size_t base = 2 * ((size_t)o * NI + i);
    tap[base]     = make_float4(vA1, vA2, __int_as_float(posA >= 2048 ? 16384 : posA * 8), 0.f);
    tap[base + 1] = make_float4(vB1, vB2, __int_as_float(posB >= 2048 ? 16384 : posB * 8), 0.f);
}

// ---------- P3: wave-exclusive-plane float2 RMW scatter + fused double cumsum^2 ----------
// Wave w owns float2 planes (w,ramp0),(w,ramp1). Lane: k=lane>>1 spike slot, ramp=lane&1.
// Byte addressing: e8 = min(t8 + p8, dcap8); dcap8 = (561+(k&7))*8 spread dustbin.
// Non-atomic RMW race-free: distinct spike times per lane within a plane.
#define PROC(TP, WV, CNT, IDX)                                                        \
    {                                                                                 \
        const int p8 = __float_as_int((TP).z);                                        \
        {                                                                             \
            int e8 = min((int)((WV) & 0xFFFFu) + p8, dcap8);                          \
            float2* cell = (float2*)((char*)accw + e8);                               \
            float2 v = *cell; v.x += (TP).x; v.y += (TP).y; *cell = v;                \
        }                                                                             \
        if ((CNT) > 32u) {                                                            \
            int e8 = min((int)((WV) >> 16) + p8, dcap8);                              \
            float2* cell = (float2*)((char*)accw + e8);                               \
            float2 v = *cell; v.x += (TP).x; v.y += (TP).y; *cell = v;                \
        }                                                                             \
        if ((CNT) > 64u) {                                                            \
            const unsigned short* sr = slist + (size_t)(b * NI + (IDX)) * SCAP;       \
            for (int kk = 64 + k; kk < (int)(CNT); kk += 32) {                        \
                int e8 = min(((int)sr[kk] << 3) + p8, dcap8);                         \
                float2* cell = (float2*)((char*)accw + e8);                           \
                float2 v = *cell; v.x += (TP).x; v.y += (TP).y; *cell = v;            \
            }                                                                         \
        }                                                                             \
    }

__global__ __launch_bounds__(256, 4) void k_scatter(const unsigned short* __restrict__ slist,
                                                    const unsigned int* __restrict__ spkw,
                                                    const unsigned int* __restrict__ counts,
                                                    const float4* __restrict__ tap,
                                                    const float* __restrict__ hg,
                                                    float* __restrict__ pot) {
    __shared__ __align__(16) float2 acc[OTILE * 2 * PLANE];  // 36,480 B
    __shared__ double pub[512];                              // 4,096 B -> 40,832: 4 blk/CU
    const int o0 = blockIdx.x * OTILE;
    const int b  = blockIdx.y;
    const int tid = threadIdx.x;
    const int w = tid >> 6, lane = tid & 63;
    const int k = lane >> 1, ramp = lane & 1;
    const int dcap8 = (561 + (k & 7)) * 8;         // spread dustbin, loop-invariant

    for (int idx = tid; idx < OTILE * PLANE; idx += 256)     // 2280 float4s = whole acc
        ((float4*)acc)[idx] = make_float4(0.f, 0.f, 0.f, 0.f);
    __syncthreads();

    float2* accw = acc + (w * 2 + ramp) * PLANE;   // my (wave, ramp) plane
    const unsigned int* wrow = spkw + (size_t)(b * NI) * 32 + k;
    const float4* trow = tap + 2 * (size_t)(o0 + w) * NI + ramp;
    const uint4* crow = (const uint4*)(counts + b * NI);

    // prefetch quad 0 (statically-named scalars -> registers; R9 lesson)
    float4 ntA = trow[0], ntB = trow[2], ntC = trow[4], ntD = trow[6];
    unsigned nwA = wrow[0], nwB = wrow[32], nwC = wrow[64], nwD = wrow[96];
    uint4 ncc = crow[0];

    const int NIQ = NI / 4;
    for (int iq = 0; iq < NIQ; ++iq) {
        const float4 tA = ntA, tB = ntB, tC = ntC, tD = ntD;
        const unsigned wA = nwA, wB = nwB, wC = nwC, wD = nwD;
        const uint4 cc = ncc;
        if (iq + 1 < NIQ) {                        // prefetch next quad
            const float4* tb = trow + (size_t)(iq + 1) * 8;
            ntA = tb[0]; ntB = tb[2]; ntC = tb[4]; ntD = tb[6];
            const unsigned int* wb = wrow + (size_t)(iq + 1) * 128;
            nwA = wb[0]; nwB = wb[32]; nwC = wb[64]; nwD = wb[96];
            ncc = crow[iq + 1];
        }
        const int i0 = iq * 4;
        PROC(tA, wA, cc.x, i0)
        PROC(tB, wB, cc.y, i0 + 1)
        PROC(tC, wC, cc.z, i0 + 2)
        PROC(tD, wD, cc.w, i0 + 3)
    }
    __syncthreads();

    // ---- cumsum^2 (double): thread (oo=w, q=lane) owns cells [9q, 9q+9) ----
    const int q = lane;
    const float2* pr0 = acc + (w * 2) * PLANE;
    const float2* pr1 = pr0 + PLANE;
    const float* hb = hg + b * NT;
    double dsv[9];
    double s1d = 0.0, s2d = 0.0;
#pragma unroll
    for (int r = 0; r < 9; ++r) {
        int e = q * 9 + r;
        double d = 0.0;
        if (e < 561) {
            float2 c0 = pr0[e], c1 = pr1[e];
            d = (double)c0.x + (double)c1.x;
            if (e >= 1) {
                float2 m0 = pr0[e - 1], m1 = pr1[e - 1];
                d += (double)m0.y + (double)m1.y;           // v2 planes: shifted +1
                if (e <= 512) d += 0.0625 * (double)hb[e - 1];   // onset histogram
            }
        }
        dsv[r] = d; s1d += d; s2d += s1d;
    }
    pub[2 * tid] = s1d; pub[2 * tid + 1] = s2d;
    __syncthreads();
    if (tid < 4) {                                 // serial carry scan per o-row
        double c1 = 0.0, c2 = 0.0;
        for (int qq = 0; qq < 64; ++qq) {
            int j = (tid << 6) + qq;
            double S1 = pub[2 * j], S2 = pub[2 * j + 1];
            pub[2 * j] = c1; pub[2 * j + 1] = c2;
            c2 += 9.0 * c1 + S2;
            c1 += S1;
        }
    }
    __syncthreads();
    {
        const double C1 = pub[2 * tid], C2 = pub[2 * tid + 1];
        double a1 = 0.0, a2 = 0.0;
        float2* rowW = acc + (w * 2) * PLANE;
#pragma unroll
        for (int r = 0; r < 9; ++r) {
            a1 += dsv[r]; a2 += a1;
            int e = q * 9 + r;
            if (e < 561) rowW[e].x = (float)(C2 + C1 * (double)(r + 1) + a2);
        }
    }
    __syncthreads();
    for (int oo = 0; oo < OTILE; ++oo)             // coalesced pot write (t fastest)
        for (int t = tid; t < TOUT; t += 256)
            pot[((size_t)(b * NO + o0 + oo)) * TOUT + t] = acc[(oo * 2) * PLANE + t + 15].x + BIAS_T;
}

// ---------- P4a: partial argmax over 128-o chunks (1152 blocks) ----------
__global__ __launch_bounds__(256) void k_argmax1(const float* __restrict__ pot,
                                                 float* __restrict__ pval,
                                                 unsigned short* __restrict__ pidx) {
    __shared__ float sv[4][64];
    __shared__ int   si[4][64];
    int b = blockIdx.y, c = blockIdx.z;
    int lane = threadIdx.x & 63, grp = threadIdx.x >> 6;
    int t = blockIdx.x * 64 + lane;
    bool valid = t < TOUT;
    float best = -1.f; int bidx = 0;
    if (valid) {
        int ob = c * 128 + grp * 32;
        for (int od = 0; od < 32; ++od) {          // ascending o + strict '>' => first max wins
            int o = ob + od;
            float v = pot[((size_t)(b * NO + o)) * TOUT + t];
            if (v > best) { best = v; bidx = o; }
        }
    }
    sv[grp][lane] = best; si[grp][lane] = bidx;
    __syncthreads();
    if (grp == 0 && valid) {
#pragma unroll
        for (int g = 1; g < 4; ++g) {              // ascending grp = ascending o
            float v = sv[g][lane];
            if (v > best) { best = v; bidx = si[g][lane]; }
        }
        pval[((size_t)(c * NB + b)) * TOUT + t] = best;
        pidx[((size_t)(c * NB + b)) * TOUT + t] = (unsigned short)bidx;
    }
}

// ---------- P4b: combine 8 chunks ----------
__global__ __launch_bounds__(64) void k_argmax2(const float* __restrict__ pval,
                                                const unsigned short* __restrict__ pidx,
                                                float* __restrict__ aval,
                                                unsigned short* __restrict__ aidx) {
    int b = blockIdx.y;
    int t = blockIdx.x * 64 + threadIdx.x;
    if (t >= TOUT) return;
    float best = -1.f; int bidx = 0;
#pragma unroll
    for (int c = 0; c < 8; ++c) {                  // ascending chunk = ascending o
        size_t idx = ((size_t)(c * NB + b)) * TOUT + t;
        float v = pval[idx];
        if (v > best) { best = v; bidx = pidx[idx]; }
    }
    aval[t * NB + b] = best;
    aidx[t * NB + b] = (unsigned short)bidx;
}

// ---------- P5: serial refractory scan (depression uniform across neurons) ----------
__global__ __launch_bounds__(256) void k_wta(const float* __restrict__ aval,
                                             const unsigned short* __restrict__ aidx,
                                             float* __restrict__ out) {
    __shared__ float lv[TOUT * NB];
    __shared__ unsigned short li[TOUT * NB];
    for (int idx = threadIdx.x; idx < TOUT * NB; idx += 256) { lv[idx] = aval[idx]; li[idx] = aidx[idx]; }
    __syncthreads();
    int b = threadIdx.x;
    if (b < NB) {
        int r = 0;
        for (int t = 0; t < TOUT; ++t) {
            float v = lv[t * NB + b];
            if (r == 0 && v > THETA_F) {
                int n = (int)li[t * NB + b];
                out[((size_t)(b * NO + n)) * TOUT + t] = 1.0f;
                r = 48;
            }
            r = max(r - 1, 0);
        }
    }
}

extern "C" void kernel_launch(void* const* d_in, const int* in_sizes, int n_in,
                              void* d_out, int out_size, void* d_ws, size_t ws_size,
                              hipStream_t stream) {
    const float* x      = (const float*)d_in[0];   // [16,1,512,512]
    const float* weight = (const float*)d_in[1];   // [1024,512]
    float* out = (float*)d_out;                    // [16,1,1024,529]
    char* ws = (char*)d_ws;
    // ws layout (~19.9 MB)
    unsigned short* slist  = (unsigned short*)(ws);            // 8192*96*2     = 1,572,864
    unsigned int*   spkw   = (unsigned int*)(ws + 1572864);    // 8192*32*4     = 1,048,576
    unsigned int*   counts = (unsigned int*)(ws + 2621440);    // 8192*4        = 32,768
    float4*         tap    = (float4*)(ws + 2654208);          // 1024*512*2*16 = 16,777,216
    float*          hg     = (float*)(ws + 19431424);          // 16*512*4      = 32,768
    float*          aval   = (float*)(ws + 19464192);          // 529*16*4      = 33,856
    unsigned short* aidx   = (unsigned short*)(ws + 19498048); // 529*16*2      = 16,928
    float*          pval   = (float*)(ws + 19514976);          // 8*16*529*4    = 270,848
    unsigned short* pidx   = (unsigned short*)(ws + 19785824); // 8*16*529*2    = 135,424

    hipMemsetAsync(hg, 0, NB * NT * sizeof(float), stream);    // before k_spikes (hist fused)
    k_spikes<<<2048, 256, 0, stream>>>(x, slist, spkw, counts, hg);
    k_taps<<<2048, 256, 0, stream>>>(weight, tap);
    k_scatter<<<dim3(NO / OTILE, NB), 256, 0, stream>>>(slist, spkw, counts, tap, hg, out);
    k_argmax1<<<dim3(9, NB, 8), 256, 0, stream>>>(out, pval, pidx);
    k_argmax2<<<dim3(9, NB), 64, 0, stream>>>(pval, pidx, aval, aidx);
    hipMemsetAsync(d_out, 0, (size_t)out_size * sizeof(float), stream);   // clear pot
    k_wta<<<1, 256, 0, stream>>>(aval, aidx, out);                        // write spikes
}